// Round 16
// baseline (100.620 us; speedup 1.0000x reference)
//
#include <hip/hip_runtime.h>
#include <math.h>

#define N_NODES 40000
#define N_EDGES 640000
#define D 128
#define BN_EPS 1e-5f
#define CAP 48                                 // bucket capacity (ushort entries)
#define NBUCKET 64
#define NB 250                                 // dst bins
#define BINW 160                               // nodes per bin (250*160 = 40000)
#define EP 2500                                // edges per partition block (256 blocks)
#define PCAP 4096                              // packed-edge capacity per bin (E=2560)
#define GN 16                                  // nodes per gather block (dynamic queue)

typedef __bf16 bf16x8 __attribute__((ext_vector_type(8)));
typedef float floatx4 __attribute__((ext_vector_type(4)));

// ---------------- phase 1: partition edges into dst bins (packed uint) --------
// Also absorbs init duties: Wt conversion (64 elems/block) + zero row (block 0).

__global__ __launch_bounds__(256) void k_part(const int* __restrict__ src,
                                              const int* __restrict__ dst,
                                              int* __restrict__ gcur,
                                              unsigned* __restrict__ pbuf,
                                              const float* __restrict__ W,
                                              unsigned short* __restrict__ Wt,
                                              unsigned* __restrict__ zrow) {
    __shared__ int lcnt[NB];
    __shared__ int lbase[NB];
    __shared__ unsigned epk[EP];               // bin<<16 | dl<<8 | rank (10 KB)
    int t = threadIdx.x;
    // distributed init work (consumers launch later; no intra-kernel dependency)
    if (t < 64) {
        int i = blockIdx.x * 64 + t;           // 256 blocks x 64 = 16384 = D*D
        int k = i >> 7, c = i & 127;
        Wt[c * D + k] = __builtin_bit_cast(unsigned short, (__bf16)W[i]);
    }
    if (blockIdx.x == 0 && t >= 64 && t < 128) zrow[t - 64] = 0u;

    for (int i = t; i < NB; i += 256) lcnt[i] = 0;
    __syncthreads();
    int e0 = blockIdx.x * EP;
    for (int r = 0; r < EP; r += 256) {
        if (r + t < EP) {
            int d = dst[e0 + r + t];
            int bin = d / BINW;
            int dl = d - bin * BINW;
            int rank = atomicAdd(&lcnt[bin], 1);    // < 256 w.h.p. (mean 10)
            epk[r + t] = ((unsigned)bin << 16) | ((unsigned)dl << 8) | (unsigned)rank;
        }
    }
    __syncthreads();
    for (int i = t; i < NB; i += 256)
        lbase[i] = atomicAdd(&gcur[i], lcnt[i]);
    __syncthreads();
    for (int r = 0; r < EP; r += 256) {
        if (r + t < EP) {
            unsigned p = epk[r + t];
            int bin = p >> 16, dl = (p >> 8) & 255, rank = p & 255;
            int pos = lbase[bin] + rank;
            if (pos < PCAP)
                pbuf[bin * PCAP + pos] =
                    (unsigned)src[e0 + r + t] | ((unsigned)dl << 16);
        }
    }
}

// ---------------- phase 2: per-bin fill via LDS staging, coalesced flush ------

__global__ __launch_bounds__(256) void k_binfill(const unsigned* __restrict__ pbuf,
                                                 const int* __restrict__ gcur,
                                                 unsigned short* __restrict__ csr,
                                                 int* __restrict__ cursor) {
    __shared__ int cur[BINW];
    __shared__ unsigned short stage[BINW * CAP];   // 15360 B
    int t = threadIdx.x;
    int bin = blockIdx.x;
    for (int i = t; i < BINW; i += 256) cur[i] = 0;
    const unsigned sv = 0x9C409C40u;               // two ushort 40000 sentinels
    for (int i = t; i < (BINW * CAP) / 2; i += 256) ((unsigned*)stage)[i] = sv;
    __syncthreads();
    int ne = min(gcur[bin], PCAP);
    const unsigned* pb = pbuf + bin * PCAP;
    for (int i = t; i < ne; i += 256) {
        unsigned p = pb[i];
        int dl = p >> 16, s = p & 0xffff;
        int slot = atomicAdd(&cur[dl], 1);         // LDS atomic
        if (slot < CAP) stage[dl * CAP + slot] = (unsigned short)s;
    }
    __syncthreads();
    unsigned* dc = (unsigned*)(csr + (size_t)bin * BINW * CAP);
    const unsigned* st = (const unsigned*)stage;
    for (int i = t; i < (BINW * CAP) / 2; i += 256) dc[i] = st[i];
    for (int i = t; i < BINW; i += 256)
        cursor[bin * BINW + i] = min(cur[i], CAP);
}

// ---------------- MFMA GEMM: hp[r][c] = bf16((x @ W)[r][c] * dinv[r]) ----------------

__global__ __launch_bounds__(256) void k_gemm(const float* __restrict__ x,
                                              const unsigned short* __restrict__ Wt,
                                              const int* __restrict__ cursor,
                                              unsigned short* __restrict__ hp) {
    __shared__ unsigned short hs[64 * D];   // 16 KB
    int wave = threadIdx.x >> 6;
    int lane = threadIdx.x & 63;
    int lm = lane & 15;
    int lg = lane >> 4;               // k-group / row-group
    int r0 = blockIdx.x * 64 + wave * 16;

    bf16x8 a[4];
    const float* xrow = x + (size_t)(r0 + lm) * D;
#pragma unroll
    for (int ks = 0; ks < 4; ++ks) {
        int k0 = ks * 32 + lg * 8;
        float4 u0 = *(const float4*)(xrow + k0);
        float4 u1 = *(const float4*)(xrow + k0 + 4);
        bf16x8 av;
        av[0] = (__bf16)u0.x; av[1] = (__bf16)u0.y;
        av[2] = (__bf16)u0.z; av[3] = (__bf16)u0.w;
        av[4] = (__bf16)u1.x; av[5] = (__bf16)u1.y;
        av[6] = (__bf16)u1.z; av[7] = (__bf16)u1.w;
        a[ks] = av;
    }
    float dv[4];
#pragma unroll
    for (int j = 0; j < 4; ++j)
        dv[j] = rsqrtf((float)(cursor[r0 + lg * 4 + j] + 1));   // +1 self-loop

    typedef unsigned short ushort8v __attribute__((ext_vector_type(8)));
#pragma unroll
    for (int nt = 0; nt < 8; ++nt) {
        floatx4 acc = {0.f, 0.f, 0.f, 0.f};
        const unsigned short* wrow = Wt + (size_t)(nt * 16 + lm) * D;
#pragma unroll
        for (int ks = 0; ks < 4; ++ks) {
            int k0 = ks * 32 + lg * 8;
            bf16x8 b = __builtin_bit_cast(bf16x8, *(const ushort8v*)(wrow + k0));
            acc = __builtin_amdgcn_mfma_f32_16x16x32_bf16(a[ks], b, acc, 0, 0, 0);
        }
#pragma unroll
        for (int j = 0; j < 4; ++j)
            hs[(wave * 16 + lg * 4 + j) * D + nt * 16 + lm] =
                __builtin_bit_cast(unsigned short, (__bf16)(acc[j] * dv[j]));
    }
    __syncthreads();
    const uint4* hs4 = (const uint4*)hs;
    uint4* out4 = (uint4*)(hp + (size_t)blockIdx.x * 64 * D);
#pragma unroll
    for (int i = 0; i < 4; ++i)
        out4[i * 256 + threadIdx.x] = hs4[i * 256 + threadIdx.x];
}

// ---------------- gather: ytmp[n] = bf16(relu((h'[n] + sum h'[s])*dinv[n] + b))
// One wave per node, dynamic LDS queue; 8-wide bursts; pads -> zero row.
// Writes packed bf16 (4B/lane) -- halves store traffic; BN stats stay f32.

__global__ __launch_bounds__(256) void k_gather(const unsigned short* __restrict__ hp,
                                                const int* __restrict__ cursor,
                                                const unsigned short* __restrict__ csr,
                                                const float* __restrict__ bvec,
                                                unsigned* __restrict__ ytmp,
                                                float* __restrict__ smulti) {
    const unsigned* h1 = (const unsigned*)hp;   // row = 64 uints (2 bf16 each)
    __shared__ int nq;
    __shared__ float2 r1[256], r2[256];
    int t = threadIdx.x;
    int lane = t & 63;
    if (t == 0) nq = 0;
    __syncthreads();

    float b0 = bvec[2 * lane], b1 = bvec[2 * lane + 1];
    float2 sum = {0.f, 0.f}, ssq = {0.f, 0.f};

    for (;;) {
        int idx = 0;
        if (lane == 0) idx = atomicAdd(&nq, 1);
        idx = __shfl(idx, 0, 64);
        if (idx >= GN) break;
        int n = blockIdx.x * GN + idx;
        unsigned su = h1[(size_t)n * 64 + lane];
        float a0 = __uint_as_float(su << 16);
        float a1 = __uint_as_float(su & 0xffff0000u);
        int cnt = cursor[n];                     // true degree (<= CAP)
        const unsigned short* seg = csr + (size_t)n * CAP;
        for (int j = 0; j < cnt; j += 8) {       // pads hit zero row
            uint4 sv = *(const uint4*)(seg + j); // 8 ushort indices (uniform addr)
            int s0 = sv.x & 0xffff, s1 = sv.x >> 16;
            int s2 = sv.y & 0xffff, s3 = sv.y >> 16;
            int s4 = sv.z & 0xffff, s5 = sv.z >> 16;
            int s6 = sv.w & 0xffff, s7 = sv.w >> 16;
            unsigned u0 = h1[(size_t)s0 * 64 + lane];
            unsigned u1 = h1[(size_t)s1 * 64 + lane];
            unsigned u2 = h1[(size_t)s2 * 64 + lane];
            unsigned u3 = h1[(size_t)s3 * 64 + lane];
            unsigned u4 = h1[(size_t)s4 * 64 + lane];
            unsigned u5 = h1[(size_t)s5 * 64 + lane];
            unsigned u6 = h1[(size_t)s6 * 64 + lane];
            unsigned u7 = h1[(size_t)s7 * 64 + lane];
            a0 += ((__uint_as_float(u0 << 16) + __uint_as_float(u1 << 16)) +
                   (__uint_as_float(u2 << 16) + __uint_as_float(u3 << 16))) +
                  ((__uint_as_float(u4 << 16) + __uint_as_float(u5 << 16)) +
                   (__uint_as_float(u6 << 16) + __uint_as_float(u7 << 16)));
            a1 += ((__uint_as_float(u0 & 0xffff0000u) + __uint_as_float(u1 & 0xffff0000u)) +
                   (__uint_as_float(u2 & 0xffff0000u) + __uint_as_float(u3 & 0xffff0000u))) +
                  ((__uint_as_float(u4 & 0xffff0000u) + __uint_as_float(u5 & 0xffff0000u)) +
                   (__uint_as_float(u6 & 0xffff0000u) + __uint_as_float(u7 & 0xffff0000u)));
        }
        float di = rsqrtf((float)(cnt + 1));
        float o0 = fmaxf(fmaf(a0, di, b0), 0.f);
        float o1 = fmaxf(fmaf(a1, di, b1), 0.f);
        unsigned short p0 = __builtin_bit_cast(unsigned short, (__bf16)o0);
        unsigned short p1 = __builtin_bit_cast(unsigned short, (__bf16)o1);
        ytmp[(size_t)n * 64 + lane] = (unsigned)p0 | ((unsigned)p1 << 16);
        sum.x += o0; sum.y += o1;
        ssq.x = fmaf(o0, o0, ssq.x);
        ssq.y = fmaf(o1, o1, ssq.y);
    }
    r1[t] = sum;
    r2[t] = ssq;
    __syncthreads();
    if (t < 64) {
        float2 A = r1[t], B = r2[t];
#pragma unroll
        for (int w = 1; w < 4; ++w) {
            float2 p = r1[w * 64 + t], q = r2[w * 64 + t];
            A.x += p.x; A.y += p.y;
            B.x += q.x; B.y += q.y;
        }
        float* sb = smulti + (blockIdx.x & (NBUCKET - 1)) * 256;
        atomicAdd(&sb[2 * t], A.x);
        atomicAdd(&sb[2 * t + 1], A.y);
        atomicAdd(&sb[128 + 2 * t], B.x);
        atomicAdd(&sb[128 + 2 * t + 1], B.y);
    }
}

// ---------------- BN finalize: y = (ytmp - mean)*rs*gamma + beta (f32 out) ------

__global__ __launch_bounds__(256) void k_bnfinal(const unsigned* __restrict__ ytmp,
                                                 float* __restrict__ y,
                                                 const float* __restrict__ smulti,
                                                 const float* __restrict__ gamma,
                                                 const float* __restrict__ beta) {
    __shared__ float sc[128], bi[128];
    {
        int t = threadIdx.x;
        float s = 0.f;
#pragma unroll 8
        for (int k = 0; k < NBUCKET; ++k) s += smulti[k * 256 + t];
        __shared__ float stats[256];
        stats[t] = s;
        __syncthreads();
        if (t < 128) {
            float invN = 1.0f / (float)N_NODES;
            float mean = stats[t] * invN;
            float var = stats[128 + t] * invN - mean * mean;
            float rs = rsqrtf(var + BN_EPS) * gamma[t];
            sc[t] = rs;
            bi[t] = beta[t] - mean * rs;
        }
    }
    __syncthreads();
    const int total = N_NODES * 64;   // packed-uint count
    for (int idx = blockIdx.x * 256 + threadIdx.x; idx < total;
         idx += gridDim.x * 256) {
        int c = idx & 63;             // uint column -> cols 2c, 2c+1
        unsigned u = ytmp[idx];
        float v0 = __uint_as_float(u << 16);
        float v1 = __uint_as_float(u & 0xffff0000u);
        float2 o;
        o.x = fmaf(v0, sc[2 * c + 0], bi[2 * c + 0]);
        o.y = fmaf(v1, sc[2 * c + 1], bi[2 * c + 1]);
        ((float2*)y)[idx] = o;
    }
}

extern "C" void kernel_launch(void* const* d_in, const int* in_sizes, int n_in,
                              void* d_out, int out_size, void* d_ws, size_t ws_size,
                              hipStream_t stream) {
    const float* x     = (const float*)d_in[0];
    const int*   ei    = (const int*)d_in[1];      // [2, E]: row0=src, row1=dst
    const float* W     = (const float*)d_in[2];
    const float* bvec  = (const float*)d_in[3];
    const float* gamma = (const float*)d_in[4];
    const float* beta  = (const float*)d_in[5];
    float* y = (float*)d_out;

    const int* src = ei;
    const int* dst = ei + N_EDGES;

    char* ws = (char*)d_ws;
    unsigned short* hp = (unsigned short*)ws;               // (N+1)*D bf16 (row N = 0)
    size_t off = (size_t)(N_NODES + 1) * D * 2;             // 16B-aligned
    unsigned short* Wt = (unsigned short*)(ws + off);       // 128*128 bf16
    off += D * D * 2;
    float* smulti = (float*)(ws + off);                     // 64*256 f32   } one
    off += NBUCKET * 256 * 4;                               //              } memset
    int* gcur = (int*)(ws + off);                           // 256 ints     } region
    off += 256 * 4;
    int* cursor = (int*)(ws + off);                         // N ints
    off += (size_t)N_NODES * 4;
    unsigned short* csr = (unsigned short*)(ws + off);      // N*CAP ushort (3.84 MB)
    off += (size_t)N_NODES * CAP * 2;
    unsigned* pbuf = (unsigned*)(ws + off);                 // NB*PCAP uints (4.1 MB)
    off += (size_t)NB * PCAP * 4;
    unsigned* ytmp = (unsigned*)(ws + off);                 // N*64 uints (10.24 MB)

    hipMemsetAsync(smulti, 0, (size_t)(NBUCKET * 256 + 256) * 4, stream);
    k_part<<<N_EDGES / EP, 256, 0, stream>>>(src, dst, gcur, pbuf, W, Wt,
                                             (unsigned*)(hp + (size_t)N_NODES * D));
    k_binfill<<<NB, 256, 0, stream>>>(pbuf, gcur, csr, cursor);
    k_gemm<<<N_NODES / 64, 256, 0, stream>>>(x, Wt, cursor, hp);
    k_gather<<<N_NODES / GN, 256, 0, stream>>>(hp, cursor, csr, bvec, ytmp, smulti);
    k_bnfinal<<<160, 256, 0, stream>>>(ytmp, y, smulti, gamma, beta);
}

// Round 17
// 100.396 us; speedup vs baseline: 1.0022x; 1.0022x over previous
//
#include <hip/hip_runtime.h>
#include <math.h>

#define N_NODES 40000
#define N_EDGES 640000
#define D 128
#define BN_EPS 1e-5f
#define CAP 48                                 // bucket capacity (ushort entries)
#define NBUCKET 64
#define NB 250                                 // dst bins
#define BINW 160                               // nodes per bin (250*160 = 40000)
#define EP 2500                                // edges per partition block (256 blocks)
#define PCAP 4096                              // packed-edge capacity per bin (E=2560)
#define GN 16                                  // nodes per gather block (dynamic queue)

typedef __bf16 bf16x8 __attribute__((ext_vector_type(8)));
typedef float floatx4 __attribute__((ext_vector_type(4)));

// ---------------- init: gcur=0, stat buckets, zero row, Wt ----------------
// grid 64 x 256 = 16384 threads (= D*D = smulti size)

__global__ __launch_bounds__(256) void k_init(int* __restrict__ gcur,
                                              float* __restrict__ smulti,
                                              unsigned* __restrict__ zrow,
                                              const float* __restrict__ W,
                                              unsigned short* __restrict__ Wt) {
    int i = blockIdx.x * 256 + threadIdx.x;
    if (i < NB) gcur[i] = 0;
    smulti[i] = 0.0f;                          // 64*256 = 16384 exactly
    if (i < 64) zrow[i] = 0u;                  // bf16 row 40000 = 64 uints
    {                                          // Wt[c][k] = bf16(W[k][c]); i < 16384
        int k = i >> 7, c = i & 127;
        Wt[c * D + k] = __builtin_bit_cast(unsigned short, (__bf16)W[i]);
    }
}

// ---------------- phase 1: partition edges into dst bins (packed uint) --------
// Single LDS-atomic pass: rank computed in pass 1, carried in the packed word.

__global__ __launch_bounds__(256) void k_part(const int* __restrict__ src,
                                              const int* __restrict__ dst,
                                              int* __restrict__ gcur,
                                              unsigned* __restrict__ pbuf) {
    __shared__ int lcnt[NB];
    __shared__ int lbase[NB];
    __shared__ unsigned epk[EP];               // bin<<16 | dl<<8 | rank (10 KB)
    int t = threadIdx.x;
    for (int i = t; i < NB; i += 256) lcnt[i] = 0;
    __syncthreads();
    int e0 = blockIdx.x * EP;
    for (int r = 0; r < EP; r += 256) {
        if (r + t < EP) {
            int d = dst[e0 + r + t];
            int bin = d / BINW;
            int dl = d - bin * BINW;
            int rank = atomicAdd(&lcnt[bin], 1);    // < 256 w.h.p. (mean 10)
            epk[r + t] = ((unsigned)bin << 16) | ((unsigned)dl << 8) | (unsigned)rank;
        }
    }
    __syncthreads();
    for (int i = t; i < NB; i += 256)
        lbase[i] = atomicAdd(&gcur[i], lcnt[i]);
    __syncthreads();
    for (int r = 0; r < EP; r += 256) {
        if (r + t < EP) {
            unsigned p = epk[r + t];
            int bin = p >> 16, dl = (p >> 8) & 255, rank = p & 255;
            int pos = lbase[bin] + rank;
            if (pos < PCAP)
                pbuf[bin * PCAP + pos] =
                    (unsigned)src[e0 + r + t] | ((unsigned)dl << 16);
        }
    }
}

// ---------------- phase 2: per-bin fill via LDS staging, coalesced flush ------

__global__ __launch_bounds__(256) void k_binfill(const unsigned* __restrict__ pbuf,
                                                 const int* __restrict__ gcur,
                                                 unsigned short* __restrict__ csr,
                                                 int* __restrict__ cursor) {
    __shared__ int cur[BINW];
    __shared__ unsigned short stage[BINW * CAP];   // 15360 B
    int t = threadIdx.x;
    int bin = blockIdx.x;
    for (int i = t; i < BINW; i += 256) cur[i] = 0;
    const unsigned sv = 0x9C409C40u;               // two ushort 40000 sentinels
    for (int i = t; i < (BINW * CAP) / 2; i += 256) ((unsigned*)stage)[i] = sv;
    __syncthreads();
    int ne = min(gcur[bin], PCAP);
    const unsigned* pb = pbuf + bin * PCAP;
    for (int i = t; i < ne; i += 256) {
        unsigned p = pb[i];
        int dl = p >> 16, s = p & 0xffff;
        int slot = atomicAdd(&cur[dl], 1);         // LDS atomic
        if (slot < CAP) stage[dl * CAP + slot] = (unsigned short)s;
    }
    __syncthreads();
    unsigned* dc = (unsigned*)(csr + (size_t)bin * BINW * CAP);
    const unsigned* st = (const unsigned*)stage;
    for (int i = t; i < (BINW * CAP) / 2; i += 256) dc[i] = st[i];
    for (int i = t; i < BINW; i += 256)
        cursor[bin * BINW + i] = min(cur[i], CAP);
}

// ---------------- MFMA GEMM: hp[r][c] = bf16((x @ W)[r][c] * dinv[r]) ----------------

__global__ __launch_bounds__(256) void k_gemm(const float* __restrict__ x,
                                              const unsigned short* __restrict__ Wt,
                                              const int* __restrict__ cursor,
                                              unsigned short* __restrict__ hp) {
    __shared__ unsigned short hs[64 * D];   // 16 KB
    int wave = threadIdx.x >> 6;
    int lane = threadIdx.x & 63;
    int lm = lane & 15;
    int lg = lane >> 4;               // k-group / row-group
    int r0 = blockIdx.x * 64 + wave * 16;

    bf16x8 a[4];
    const float* xrow = x + (size_t)(r0 + lm) * D;
#pragma unroll
    for (int ks = 0; ks < 4; ++ks) {
        int k0 = ks * 32 + lg * 8;
        float4 u0 = *(const float4*)(xrow + k0);
        float4 u1 = *(const float4*)(xrow + k0 + 4);
        bf16x8 av;
        av[0] = (__bf16)u0.x; av[1] = (__bf16)u0.y;
        av[2] = (__bf16)u0.z; av[3] = (__bf16)u0.w;
        av[4] = (__bf16)u1.x; av[5] = (__bf16)u1.y;
        av[6] = (__bf16)u1.z; av[7] = (__bf16)u1.w;
        a[ks] = av;
    }
    float dv[4];
#pragma unroll
    for (int j = 0; j < 4; ++j)
        dv[j] = rsqrtf((float)(cursor[r0 + lg * 4 + j] + 1));   // +1 self-loop

    typedef unsigned short ushort8v __attribute__((ext_vector_type(8)));
#pragma unroll
    for (int nt = 0; nt < 8; ++nt) {
        floatx4 acc = {0.f, 0.f, 0.f, 0.f};
        const unsigned short* wrow = Wt + (size_t)(nt * 16 + lm) * D;
#pragma unroll
        for (int ks = 0; ks < 4; ++ks) {
            int k0 = ks * 32 + lg * 8;
            bf16x8 b = __builtin_bit_cast(bf16x8, *(const ushort8v*)(wrow + k0));
            acc = __builtin_amdgcn_mfma_f32_16x16x32_bf16(a[ks], b, acc, 0, 0, 0);
        }
#pragma unroll
        for (int j = 0; j < 4; ++j)
            hs[(wave * 16 + lg * 4 + j) * D + nt * 16 + lm] =
                __builtin_bit_cast(unsigned short, (__bf16)(acc[j] * dv[j]));
    }
    __syncthreads();
    const uint4* hs4 = (const uint4*)hs;
    uint4* out4 = (uint4*)(hp + (size_t)blockIdx.x * 64 * D);
#pragma unroll
    for (int i = 0; i < 4; ++i)
        out4[i * 256 + threadIdx.x] = hs4[i * 256 + threadIdx.x];
}

// ---------------- gather: ytmp[n] = bf16(relu((h'[n] + sum h'[s])*dinv[n] + b))
// One wave per node, dynamic LDS queue; 8-wide bursts; pads -> zero row.
// Writes packed bf16 (4B/lane); BN stats stay f32.

__global__ __launch_bounds__(256) void k_gather(const unsigned short* __restrict__ hp,
                                                const int* __restrict__ cursor,
                                                const unsigned short* __restrict__ csr,
                                                const float* __restrict__ bvec,
                                                unsigned* __restrict__ ytmp,
                                                float* __restrict__ smulti) {
    const unsigned* h1 = (const unsigned*)hp;   // row = 64 uints (2 bf16 each)
    __shared__ int nq;
    __shared__ float2 r1[256], r2[256];
    int t = threadIdx.x;
    int lane = t & 63;
    if (t == 0) nq = 0;
    __syncthreads();

    float b0 = bvec[2 * lane], b1 = bvec[2 * lane + 1];
    float2 sum = {0.f, 0.f}, ssq = {0.f, 0.f};

    for (;;) {
        int idx = 0;
        if (lane == 0) idx = atomicAdd(&nq, 1);
        idx = __shfl(idx, 0, 64);
        if (idx >= GN) break;
        int n = blockIdx.x * GN + idx;
        unsigned su = h1[(size_t)n * 64 + lane];
        float a0 = __uint_as_float(su << 16);
        float a1 = __uint_as_float(su & 0xffff0000u);
        int cnt = cursor[n];                     // true degree (<= CAP)
        const unsigned short* seg = csr + (size_t)n * CAP;
        for (int j = 0; j < cnt; j += 8) {       // pads hit zero row
            uint4 sv = *(const uint4*)(seg + j); // 8 ushort indices (uniform addr)
            int s0 = sv.x & 0xffff, s1 = sv.x >> 16;
            int s2 = sv.y & 0xffff, s3 = sv.y >> 16;
            int s4 = sv.z & 0xffff, s5 = sv.z >> 16;
            int s6 = sv.w & 0xffff, s7 = sv.w >> 16;
            unsigned u0 = h1[(size_t)s0 * 64 + lane];
            unsigned u1 = h1[(size_t)s1 * 64 + lane];
            unsigned u2 = h1[(size_t)s2 * 64 + lane];
            unsigned u3 = h1[(size_t)s3 * 64 + lane];
            unsigned u4 = h1[(size_t)s4 * 64 + lane];
            unsigned u5 = h1[(size_t)s5 * 64 + lane];
            unsigned u6 = h1[(size_t)s6 * 64 + lane];
            unsigned u7 = h1[(size_t)s7 * 64 + lane];
            a0 += ((__uint_as_float(u0 << 16) + __uint_as_float(u1 << 16)) +
                   (__uint_as_float(u2 << 16) + __uint_as_float(u3 << 16))) +
                  ((__uint_as_float(u4 << 16) + __uint_as_float(u5 << 16)) +
                   (__uint_as_float(u6 << 16) + __uint_as_float(u7 << 16)));
            a1 += ((__uint_as_float(u0 & 0xffff0000u) + __uint_as_float(u1 & 0xffff0000u)) +
                   (__uint_as_float(u2 & 0xffff0000u) + __uint_as_float(u3 & 0xffff0000u))) +
                  ((__uint_as_float(u4 & 0xffff0000u) + __uint_as_float(u5 & 0xffff0000u)) +
                   (__uint_as_float(u6 & 0xffff0000u) + __uint_as_float(u7 & 0xffff0000u)));
        }
        float di = rsqrtf((float)(cnt + 1));
        float o0 = fmaxf(fmaf(a0, di, b0), 0.f);
        float o1 = fmaxf(fmaf(a1, di, b1), 0.f);
        unsigned short p0 = __builtin_bit_cast(unsigned short, (__bf16)o0);
        unsigned short p1 = __builtin_bit_cast(unsigned short, (__bf16)o1);
        ytmp[(size_t)n * 64 + lane] = (unsigned)p0 | ((unsigned)p1 << 16);
        sum.x += o0; sum.y += o1;
        ssq.x = fmaf(o0, o0, ssq.x);
        ssq.y = fmaf(o1, o1, ssq.y);
    }
    r1[t] = sum;
    r2[t] = ssq;
    __syncthreads();
    if (t < 64) {
        float2 A = r1[t], B = r2[t];
#pragma unroll
        for (int w = 1; w < 4; ++w) {
            float2 p = r1[w * 64 + t], q = r2[w * 64 + t];
            A.x += p.x; A.y += p.y;
            B.x += q.x; B.y += q.y;
        }
        float* sb = smulti + (blockIdx.x & (NBUCKET - 1)) * 256;
        atomicAdd(&sb[2 * t], A.x);
        atomicAdd(&sb[2 * t + 1], A.y);
        atomicAdd(&sb[128 + 2 * t], B.x);
        atomicAdd(&sb[128 + 2 * t + 1], B.y);
    }
}

// ---------------- BN finalize: y = (ytmp - mean)*rs*gamma + beta (f32 out) ------

__global__ __launch_bounds__(256) void k_bnfinal(const unsigned* __restrict__ ytmp,
                                                 float* __restrict__ y,
                                                 const float* __restrict__ smulti,
                                                 const float* __restrict__ gamma,
                                                 const float* __restrict__ beta) {
    __shared__ float sc[128], bi[128];
    {
        int t = threadIdx.x;
        float s = 0.f;
#pragma unroll 8
        for (int k = 0; k < NBUCKET; ++k) s += smulti[k * 256 + t];
        __shared__ float stats[256];
        stats[t] = s;
        __syncthreads();
        if (t < 128) {
            float invN = 1.0f / (float)N_NODES;
            float mean = stats[t] * invN;
            float var = stats[128 + t] * invN - mean * mean;
            float rs = rsqrtf(var + BN_EPS) * gamma[t];
            sc[t] = rs;
            bi[t] = beta[t] - mean * rs;
        }
    }
    __syncthreads();
    const int total = N_NODES * 64;   // packed-uint count
    for (int idx = blockIdx.x * 256 + threadIdx.x; idx < total;
         idx += gridDim.x * 256) {
        int c = idx & 63;             // uint column -> cols 2c, 2c+1
        unsigned u = ytmp[idx];
        float v0 = __uint_as_float(u << 16);
        float v1 = __uint_as_float(u & 0xffff0000u);
        float2 o;
        o.x = fmaf(v0, sc[2 * c + 0], bi[2 * c + 0]);
        o.y = fmaf(v1, sc[2 * c + 1], bi[2 * c + 1]);
        ((float2*)y)[idx] = o;
    }
}

extern "C" void kernel_launch(void* const* d_in, const int* in_sizes, int n_in,
                              void* d_out, int out_size, void* d_ws, size_t ws_size,
                              hipStream_t stream) {
    const float* x     = (const float*)d_in[0];
    const int*   ei    = (const int*)d_in[1];      // [2, E]: row0=src, row1=dst
    const float* W     = (const float*)d_in[2];
    const float* bvec  = (const float*)d_in[3];
    const float* gamma = (const float*)d_in[4];
    const float* beta  = (const float*)d_in[5];
    float* y = (float*)d_out;

    const int* src = ei;
    const int* dst = ei + N_EDGES;

    char* ws = (char*)d_ws;
    unsigned short* hp = (unsigned short*)ws;               // (N+1)*D bf16 (row N = 0)
    size_t off = (size_t)(N_NODES + 1) * D * 2;             // 16B-aligned
    unsigned short* Wt = (unsigned short*)(ws + off);       // 128*128 bf16
    off += D * D * 2;
    float* smulti = (float*)(ws + off);                     // 64*256 f32
    off += NBUCKET * 256 * 4;
    int* gcur = (int*)(ws + off);                           // 256 ints
    off += 256 * 4;
    int* cursor = (int*)(ws + off);                         // N ints
    off += (size_t)N_NODES * 4;
    unsigned short* csr = (unsigned short*)(ws + off);      // N*CAP ushort (3.84 MB)
    off += (size_t)N_NODES * CAP * 2;
    unsigned* pbuf = (unsigned*)(ws + off);                 // NB*PCAP uints (4.1 MB)
    off += (size_t)NB * PCAP * 4;
    unsigned* ytmp = (unsigned*)(ws + off);                 // N*64 uints (10.24 MB)

    k_init<<<64, 256, 0, stream>>>(gcur, smulti,
                                   (unsigned*)(hp + (size_t)N_NODES * D), W, Wt);
    k_part<<<N_EDGES / EP, 256, 0, stream>>>(src, dst, gcur, pbuf);
    k_binfill<<<NB, 256, 0, stream>>>(pbuf, gcur, csr, cursor);
    k_gemm<<<N_NODES / 64, 256, 0, stream>>>(x, Wt, cursor, hp);
    k_gather<<<N_NODES / GN, 256, 0, stream>>>(hp, cursor, csr, bvec, ytmp, smulti);
    k_bnfinal<<<160, 256, 0, stream>>>(ytmp, y, smulti, gamma, beta);
}

// Round 18
// 91.258 us; speedup vs baseline: 1.1026x; 1.1001x over previous
//
#include <hip/hip_runtime.h>
#include <math.h>

#define N_NODES 40000
#define N_EDGES 640000
#define D 128
#define BN_EPS 1e-5f
#define CAP 48                                 // bucket capacity (ushort entries)
#define NBUCKET 64
#define NB 250                                 // dst bins
#define BINW 160                               // nodes per bin (250*160 = 40000)
#define EP 2500                                // edges per partition block (256 blocks)
#define PCAP 4096                              // packed-edge capacity per bin (E=2560)
#define GN 16                                  // nodes per gather block (dynamic queue)

typedef __bf16 bf16x8 __attribute__((ext_vector_type(8)));
typedef float floatx4 __attribute__((ext_vector_type(4)));

// ---------------- init: gcur=0, stat buckets, zero row, Wt ----------------
// grid 64 x 256 = 16384 threads (= D*D = smulti size)

__global__ __launch_bounds__(256) void k_init(int* __restrict__ gcur,
                                              float* __restrict__ smulti,
                                              unsigned* __restrict__ zrow,
                                              const float* __restrict__ W,
                                              unsigned short* __restrict__ Wt) {
    int i = blockIdx.x * 256 + threadIdx.x;
    if (i < NB) gcur[i] = 0;
    smulti[i] = 0.0f;                          // 64*256 = 16384 exactly
    if (i < 64) zrow[i] = 0u;                  // bf16 row 40000 = 64 uints
    {                                          // Wt[c][k] = bf16(W[k][c]); i < 16384
        int k = i >> 7, c = i & 127;
        Wt[c * D + k] = __builtin_bit_cast(unsigned short, (__bf16)W[i]);
    }
}

// ---------------- phase 1: partition edges into dst bins (packed uint) --------
// Single LDS-atomic pass: rank computed in pass 1, carried in the packed word.

__global__ __launch_bounds__(256) void k_part(const int* __restrict__ src,
                                              const int* __restrict__ dst,
                                              int* __restrict__ gcur,
                                              unsigned* __restrict__ pbuf) {
    __shared__ int lcnt[NB];
    __shared__ int lbase[NB];
    __shared__ unsigned epk[EP];               // bin<<16 | dl<<8 | rank (10 KB)
    int t = threadIdx.x;
    for (int i = t; i < NB; i += 256) lcnt[i] = 0;
    __syncthreads();
    int e0 = blockIdx.x * EP;
    for (int r = 0; r < EP; r += 256) {
        if (r + t < EP) {
            int d = dst[e0 + r + t];
            int bin = d / BINW;
            int dl = d - bin * BINW;
            int rank = atomicAdd(&lcnt[bin], 1);    // < 256 w.h.p. (mean 10)
            epk[r + t] = ((unsigned)bin << 16) | ((unsigned)dl << 8) | (unsigned)rank;
        }
    }
    __syncthreads();
    for (int i = t; i < NB; i += 256)
        lbase[i] = atomicAdd(&gcur[i], lcnt[i]);
    __syncthreads();
    for (int r = 0; r < EP; r += 256) {
        if (r + t < EP) {
            unsigned p = epk[r + t];
            int bin = p >> 16, dl = (p >> 8) & 255, rank = p & 255;
            int pos = lbase[bin] + rank;
            if (pos < PCAP)
                pbuf[bin * PCAP + pos] =
                    (unsigned)src[e0 + r + t] | ((unsigned)dl << 16);
        }
    }
}

// ---------------- phase 2: per-bin fill via LDS staging, coalesced flush ------

__global__ __launch_bounds__(256) void k_binfill(const unsigned* __restrict__ pbuf,
                                                 const int* __restrict__ gcur,
                                                 unsigned short* __restrict__ csr,
                                                 int* __restrict__ cursor) {
    __shared__ int cur[BINW];
    __shared__ unsigned short stage[BINW * CAP];   // 15360 B
    int t = threadIdx.x;
    int bin = blockIdx.x;
    for (int i = t; i < BINW; i += 256) cur[i] = 0;
    const unsigned sv = 0x9C409C40u;               // two ushort 40000 sentinels
    for (int i = t; i < (BINW * CAP) / 2; i += 256) ((unsigned*)stage)[i] = sv;
    __syncthreads();
    int ne = min(gcur[bin], PCAP);
    const unsigned* pb = pbuf + bin * PCAP;
    for (int i = t; i < ne; i += 256) {
        unsigned p = pb[i];
        int dl = p >> 16, s = p & 0xffff;
        int slot = atomicAdd(&cur[dl], 1);         // LDS atomic
        if (slot < CAP) stage[dl * CAP + slot] = (unsigned short)s;
    }
    __syncthreads();
    unsigned* dc = (unsigned*)(csr + (size_t)bin * BINW * CAP);
    const unsigned* st = (const unsigned*)stage;
    for (int i = t; i < (BINW * CAP) / 2; i += 256) dc[i] = st[i];
    for (int i = t; i < BINW; i += 256)
        cursor[bin * BINW + i] = min(cur[i], CAP);
}

// ---------------- MFMA GEMM: hp[r][c] = bf16((x @ W)[r][c] * dinv[r]) ----------------

__global__ __launch_bounds__(256) void k_gemm(const float* __restrict__ x,
                                              const unsigned short* __restrict__ Wt,
                                              const int* __restrict__ cursor,
                                              unsigned short* __restrict__ hp) {
    __shared__ unsigned short hs[64 * D];   // 16 KB
    int wave = threadIdx.x >> 6;
    int lane = threadIdx.x & 63;
    int lm = lane & 15;
    int lg = lane >> 4;               // k-group / row-group
    int r0 = blockIdx.x * 64 + wave * 16;

    bf16x8 a[4];
    const float* xrow = x + (size_t)(r0 + lm) * D;
#pragma unroll
    for (int ks = 0; ks < 4; ++ks) {
        int k0 = ks * 32 + lg * 8;
        float4 u0 = *(const float4*)(xrow + k0);
        float4 u1 = *(const float4*)(xrow + k0 + 4);
        bf16x8 av;
        av[0] = (__bf16)u0.x; av[1] = (__bf16)u0.y;
        av[2] = (__bf16)u0.z; av[3] = (__bf16)u0.w;
        av[4] = (__bf16)u1.x; av[5] = (__bf16)u1.y;
        av[6] = (__bf16)u1.z; av[7] = (__bf16)u1.w;
        a[ks] = av;
    }
    float dv[4];
#pragma unroll
    for (int j = 0; j < 4; ++j)
        dv[j] = rsqrtf((float)(cursor[r0 + lg * 4 + j] + 1));   // +1 self-loop

    typedef unsigned short ushort8v __attribute__((ext_vector_type(8)));
#pragma unroll
    for (int nt = 0; nt < 8; ++nt) {
        floatx4 acc = {0.f, 0.f, 0.f, 0.f};
        const unsigned short* wrow = Wt + (size_t)(nt * 16 + lm) * D;
#pragma unroll
        for (int ks = 0; ks < 4; ++ks) {
            int k0 = ks * 32 + lg * 8;
            bf16x8 b = __builtin_bit_cast(bf16x8, *(const ushort8v*)(wrow + k0));
            acc = __builtin_amdgcn_mfma_f32_16x16x32_bf16(a[ks], b, acc, 0, 0, 0);
        }
#pragma unroll
        for (int j = 0; j < 4; ++j)
            hs[(wave * 16 + lg * 4 + j) * D + nt * 16 + lm] =
                __builtin_bit_cast(unsigned short, (__bf16)(acc[j] * dv[j]));
    }
    __syncthreads();
    const uint4* hs4 = (const uint4*)hs;
    uint4* out4 = (uint4*)(hp + (size_t)blockIdx.x * 64 * D);
#pragma unroll
    for (int i = 0; i < 4; ++i)
        out4[i * 256 + threadIdx.x] = hs4[i * 256 + threadIdx.x];
}

// ---------------- gather: y[n] = relu((h'[n] + sum h'[s]) * dinv[n] + b) ------
// One wave per node, dynamic LDS queue; 8-wide bursts; pads -> zero row.
// Writes f32 y directly (8B/lane float2) -- the bf16-ytmp split regressed (R16/R17).

__global__ __launch_bounds__(256) void k_gather(const unsigned short* __restrict__ hp,
                                                const int* __restrict__ cursor,
                                                const unsigned short* __restrict__ csr,
                                                const float* __restrict__ bvec,
                                                float* __restrict__ y,
                                                float* __restrict__ smulti) {
    const unsigned* h1 = (const unsigned*)hp;   // row = 64 uints (2 bf16 each)
    __shared__ int nq;
    __shared__ float2 r1[256], r2[256];
    int t = threadIdx.x;
    int lane = t & 63;
    if (t == 0) nq = 0;
    __syncthreads();

    float b0 = bvec[2 * lane], b1 = bvec[2 * lane + 1];
    float2 sum = {0.f, 0.f}, ssq = {0.f, 0.f};

    for (;;) {
        int idx = 0;
        if (lane == 0) idx = atomicAdd(&nq, 1);
        idx = __shfl(idx, 0, 64);
        if (idx >= GN) break;
        int n = blockIdx.x * GN + idx;
        unsigned su = h1[(size_t)n * 64 + lane];
        float a0 = __uint_as_float(su << 16);
        float a1 = __uint_as_float(su & 0xffff0000u);
        int cnt = cursor[n];                     // true degree (<= CAP)
        const unsigned short* seg = csr + (size_t)n * CAP;
        for (int j = 0; j < cnt; j += 8) {       // pads hit zero row
            uint4 sv = *(const uint4*)(seg + j); // 8 ushort indices (uniform addr)
            int s0 = sv.x & 0xffff, s1 = sv.x >> 16;
            int s2 = sv.y & 0xffff, s3 = sv.y >> 16;
            int s4 = sv.z & 0xffff, s5 = sv.z >> 16;
            int s6 = sv.w & 0xffff, s7 = sv.w >> 16;
            unsigned u0 = h1[(size_t)s0 * 64 + lane];
            unsigned u1 = h1[(size_t)s1 * 64 + lane];
            unsigned u2 = h1[(size_t)s2 * 64 + lane];
            unsigned u3 = h1[(size_t)s3 * 64 + lane];
            unsigned u4 = h1[(size_t)s4 * 64 + lane];
            unsigned u5 = h1[(size_t)s5 * 64 + lane];
            unsigned u6 = h1[(size_t)s6 * 64 + lane];
            unsigned u7 = h1[(size_t)s7 * 64 + lane];
            a0 += ((__uint_as_float(u0 << 16) + __uint_as_float(u1 << 16)) +
                   (__uint_as_float(u2 << 16) + __uint_as_float(u3 << 16))) +
                  ((__uint_as_float(u4 << 16) + __uint_as_float(u5 << 16)) +
                   (__uint_as_float(u6 << 16) + __uint_as_float(u7 << 16)));
            a1 += ((__uint_as_float(u0 & 0xffff0000u) + __uint_as_float(u1 & 0xffff0000u)) +
                   (__uint_as_float(u2 & 0xffff0000u) + __uint_as_float(u3 & 0xffff0000u))) +
                  ((__uint_as_float(u4 & 0xffff0000u) + __uint_as_float(u5 & 0xffff0000u)) +
                   (__uint_as_float(u6 & 0xffff0000u) + __uint_as_float(u7 & 0xffff0000u)));
        }
        float di = rsqrtf((float)(cnt + 1));
        float o0 = fmaxf(fmaf(a0, di, b0), 0.f);
        float o1 = fmaxf(fmaf(a1, di, b1), 0.f);
        ((float2*)(y + (size_t)n * D))[lane] = make_float2(o0, o1);
        sum.x += o0; sum.y += o1;
        ssq.x = fmaf(o0, o0, ssq.x);
        ssq.y = fmaf(o1, o1, ssq.y);
    }
    r1[t] = sum;
    r2[t] = ssq;
    __syncthreads();
    if (t < 64) {
        float2 A = r1[t], B = r2[t];
#pragma unroll
        for (int w = 1; w < 4; ++w) {
            float2 p = r1[w * 64 + t], q = r2[w * 64 + t];
            A.x += p.x; A.y += p.y;
            B.x += q.x; B.y += q.y;
        }
        float* sb = smulti + (blockIdx.x & (NBUCKET - 1)) * 256;
        atomicAdd(&sb[2 * t], A.x);
        atomicAdd(&sb[2 * t + 1], A.y);
        atomicAdd(&sb[128 + 2 * t], B.x);
        atomicAdd(&sb[128 + 2 * t + 1], B.y);
    }
}

// ---------------- BN finalize (in place on y); reduces buckets once per block ------

__global__ __launch_bounds__(256) void k_bnfinal(float* __restrict__ y,
                                                 const float* __restrict__ smulti,
                                                 const float* __restrict__ gamma,
                                                 const float* __restrict__ beta) {
    __shared__ float sc[128], bi[128];
    {
        int t = threadIdx.x;
        float s = 0.f;
#pragma unroll 8
        for (int k = 0; k < NBUCKET; ++k) s += smulti[k * 256 + t];
        __shared__ float stats[256];
        stats[t] = s;
        __syncthreads();
        if (t < 128) {
            float invN = 1.0f / (float)N_NODES;
            float mean = stats[t] * invN;
            float var = stats[128 + t] * invN - mean * mean;
            float rs = rsqrtf(var + BN_EPS) * gamma[t];
            sc[t] = rs;
            bi[t] = beta[t] - mean * rs;
        }
    }
    __syncthreads();
    const int total = N_NODES * 32;   // float4 count
    for (int idx = blockIdx.x * 256 + threadIdx.x; idx < total;
         idx += gridDim.x * 256) {
        int c = idx & 31;
        float4 v = ((const float4*)y)[idx];
        int d0 = 4 * c;
        v.x = fmaf(v.x, sc[d0 + 0], bi[d0 + 0]);
        v.y = fmaf(v.y, sc[d0 + 1], bi[d0 + 1]);
        v.z = fmaf(v.z, sc[d0 + 2], bi[d0 + 2]);
        v.w = fmaf(v.w, sc[d0 + 3], bi[d0 + 3]);
        ((float4*)y)[idx] = v;
    }
}

extern "C" void kernel_launch(void* const* d_in, const int* in_sizes, int n_in,
                              void* d_out, int out_size, void* d_ws, size_t ws_size,
                              hipStream_t stream) {
    const float* x     = (const float*)d_in[0];
    const int*   ei    = (const int*)d_in[1];      // [2, E]: row0=src, row1=dst
    const float* W     = (const float*)d_in[2];
    const float* bvec  = (const float*)d_in[3];
    const float* gamma = (const float*)d_in[4];
    const float* beta  = (const float*)d_in[5];
    float* y = (float*)d_out;

    const int* src = ei;
    const int* dst = ei + N_EDGES;

    char* ws = (char*)d_ws;
    unsigned short* hp = (unsigned short*)ws;               // (N+1)*D bf16 (row N = 0)
    size_t off = (size_t)(N_NODES + 1) * D * 2;             // 16B-aligned
    unsigned short* Wt = (unsigned short*)(ws + off);       // 128*128 bf16
    off += D * D * 2;
    float* smulti = (float*)(ws + off);                     // 64*256 f32
    off += NBUCKET * 256 * 4;
    int* gcur = (int*)(ws + off);                           // 256 ints
    off += 256 * 4;
    int* cursor = (int*)(ws + off);                         // N ints
    off += (size_t)N_NODES * 4;
    unsigned short* csr = (unsigned short*)(ws + off);      // N*CAP ushort (3.84 MB)
    off += (size_t)N_NODES * CAP * 2;
    unsigned* pbuf = (unsigned*)(ws + off);                 // NB*PCAP uints (4.1 MB)

    k_init<<<64, 256, 0, stream>>>(gcur, smulti,
                                   (unsigned*)(hp + (size_t)N_NODES * D), W, Wt);
    k_part<<<N_EDGES / EP, 256, 0, stream>>>(src, dst, gcur, pbuf);
    k_binfill<<<NB, 256, 0, stream>>>(pbuf, gcur, csr, cursor);
    k_gemm<<<N_NODES / 64, 256, 0, stream>>>(x, Wt, cursor, hp);
    k_gather<<<N_NODES / GN, 256, 0, stream>>>(hp, cursor, csr, bvec, y, smulti);
    k_bnfinal<<<160, 256, 0, stream>>>(y, smulti, gamma, beta);
}